// Round 15
// baseline (329.279 us; speedup 1.0000x reference)
//
#include <hip/hip_runtime.h>
#include <float.h>
#include <stddef.h>
#include <stdint.h>

#define DIN_   1280
#define DEMB_  512
#define NBAT_  32
#define TA_    128
#define TB_    1024
#define LN_EPS_ 1e-5f

using short8  = __attribute__((ext_vector_type(8))) short;
using ushort8 = __attribute__((ext_vector_type(8))) unsigned short;
using f32x4   = __attribute__((ext_vector_type(4))) float;

typedef const __attribute__((address_space(1))) unsigned int gu32;
typedef __attribute__((address_space(3))) unsigned int lu32;

__device__ __forceinline__ void gld_lds16(const void* g, void* l) {
    __builtin_amdgcn_global_load_lds((gu32*)g, (lu32*)l, 16, 0, 0);
}

__device__ __forceinline__ unsigned short f2bf(float x) {
    unsigned u = __float_as_uint(x);
    u += 0x7FFFu + ((u >> 16) & 1u);
    return (unsigned short)(u >> 16);
}
__device__ __forceinline__ float bf2f(unsigned short u) {
    return __uint_as_float((unsigned)u << 16);
}
__device__ __forceinline__ int clampi(int v, int hi) {
    return v < 0 ? 0 : (v > hi ? hi : v);
}

// ---------------- compaction indices ----------------
__global__ __launch_bounds__(64) void compact_idx_kernel(
    const int* __restrict__ mask, int T, int* __restrict__ idx, int* __restrict__ cnt)
{
    const int b = blockIdx.x, lane = threadIdx.x;
    const int base = b * T;
    int run = 0;
    for (int c = 0; c < T; c += 64) {
        int m = mask[base + c + lane] != 0;
        unsigned long long bal = __ballot(m);
        int pos = run + __popcll(bal & ((1ull << lane) - 1ull));
        idx[base + c + lane] = m ? pos : -1;
        run += __popcll(bal);
    }
    if (lane == 0) cnt[b] = run;
}

__global__ __launch_bounds__(64) void offsets_kernel(
    const int* __restrict__ cntA, const int* __restrict__ cntB,
    int* __restrict__ offA, int* __restrict__ offB, int* __restrict__ tot)
{
    if (threadIdx.x == 0) {
        int s = 0;
        for (int i = 0; i < NBAT_; ++i) { offA[i] = s; s += cntA[i]; }
        tot[0] = s;
        s = 0;
        for (int i = 0; i < NBAT_; ++i) { offB[i] = s; s += cntB[i]; }
        tot[1] = s;
    }
}

__global__ __launch_bounds__(256) void srcrows_kernel(
    const int* __restrict__ idx, const int* __restrict__ off, int shift,
    int* __restrict__ srcrows)
{
    int r = blockIdx.x * 256 + threadIdx.x;
    int d = idx[r];
    if (d >= 0) srcrows[off[r >> shift] + d] = r;
}

// ---------------- weight transpose+convert (batched) ----------------
struct WPack { const float* src[4]; unsigned short* dst[4]; };
__global__ __launch_bounds__(256) void wtrans_multi_kernel(WPack p, int K, int N)
{
    __shared__ float tile[32][33];
    const float* W = p.src[blockIdx.z];
    unsigned short* Wt = p.dst[blockIdx.z];
    const int k0 = blockIdx.x * 32, n0 = blockIdx.y * 32;
    const int r = threadIdx.x >> 5, c = threadIdx.x & 31;
    #pragma unroll
    for (int i = 0; i < 4; ++i)
        tile[r + i * 8][c] = W[(size_t)(k0 + r + i * 8) * N + n0 + c];
    __syncthreads();
    #pragma unroll
    for (int i = 0; i < 4; ++i)
        Wt[(size_t)(n0 + r + i * 8) * K + k0 + c] = f2bf(tile[c][r + i * 8]);
}

// ---------------- dual-side parameter packs ----------------
struct EncDual {
    const unsigned short* A[2];
    const unsigned short* Wt[2];
    const float* bias[2];
    unsigned short* C[2];
    const int* Nr[2];
};
struct ProjDual {
    const float* A[2];
    const unsigned short* Wt[2];
    const float* bias[2];
    unsigned short* C[2];
    const int* srcrows[2];
    const int* Nr[2];
    int Mmax[2];
};
struct LnDual { unsigned short* h[2]; const float* g[2]; const float* b[2]; const int* Nr[2]; };
struct L2Dual { const unsigned short* h[2]; unsigned short* o[2]; const int* Nr[2]; };

// ---------------- encoder GEMM (dual), A=bf16 compacted [*,K] ----------------
template<int K, bool RELU>
__global__ __launch_bounds__(512, 4) void egemm_bf16_dual(EncDual P)
{
    const int side = blockIdx.y;
    const int bid = blockIdx.x;
    const int row0 = (bid >> 2) * 128, col0 = (bid & 3) * 128;
    if (row0 >= *P.Nr[side]) return;
    const unsigned short* A = P.A[side];
    const unsigned short* Wt = P.Wt[side];
    const float* bias = P.bias[side];
    unsigned short* C = P.C[side];

    __shared__ __align__(16) unsigned char Abuf[128 * 64 * 2];
    __shared__ __align__(16) unsigned char Bbuf[128 * 64 * 2];
    const int t = threadIdx.x;
    const int wave = t >> 6, lane = t & 63;
    const int wr = wave >> 2, wc = wave & 3;
    const int cl = lane & 15, rg = lane >> 4;

    const int pr0 = t >> 3, pq0 = t & 7;
    const int pr1 = pr0 + 64;
    const int ks0 = ((pq0 ^ (pr0 & 7)) * 8);
    const int ks1 = ((pq0 ^ (pr1 & 7)) * 8);
    const unsigned short* Aglob = A + (size_t)row0 * K;
    const unsigned short* Bglob = Wt + (size_t)col0 * K;

    int aoff[4], asw[4], boff[2], bsw[2];
    #pragma unroll
    for (int m = 0; m < 4; ++m) {
        int r = wr * 64 + m * 16 + cl;
        aoff[m] = r * 128; asw[m] = (r & 7) << 4;
    }
    #pragma unroll
    for (int n = 0; n < 2; ++n) {
        int c = wc * 32 + n * 16 + cl;
        boff[n] = c * 128; bsw[n] = (c & 7) << 4;
    }

    f32x4 acc[4][2];
    #pragma unroll
    for (int m = 0; m < 4; ++m) {
        acc[m][0] = (f32x4){0.f, 0.f, 0.f, 0.f};
        acc[m][1] = (f32x4){0.f, 0.f, 0.f, 0.f};
    }
    for (int k0 = 0; k0 < K; k0 += 64) {
        gld_lds16(Aglob + (size_t)pr0 * K + k0 + ks0, Abuf + t * 16);
        gld_lds16(Aglob + (size_t)pr1 * K + k0 + ks1, Abuf + (t + 512) * 16);
        gld_lds16(Bglob + (size_t)pr0 * K + k0 + ks0, Bbuf + t * 16);
        gld_lds16(Bglob + (size_t)pr1 * K + k0 + ks1, Bbuf + (t + 512) * 16);
        __syncthreads();
        #pragma unroll
        for (int h = 0; h < 2; ++h) {
            const int cb = h * 64 + rg * 16;
            short8 av[4], bv[2];
            #pragma unroll
            for (int m = 0; m < 4; ++m)
                av[m] = *(const short8*)(Abuf + aoff[m] + (cb ^ asw[m]));
            #pragma unroll
            for (int n = 0; n < 2; ++n)
                bv[n] = *(const short8*)(Bbuf + boff[n] + (cb ^ bsw[n]));
            #pragma unroll
            for (int m = 0; m < 4; ++m)
                #pragma unroll
                for (int n = 0; n < 2; ++n)
                    acc[m][n] = __builtin_amdgcn_mfma_f32_16x16x32_bf16(
                        av[m], bv[n], acc[m][n], 0, 0, 0);
        }
        __syncthreads();
    }
    const float b0 = bias[col0 + wc * 32 + cl];
    const float b1 = bias[col0 + wc * 32 + 16 + cl];
    #pragma unroll
    for (int m = 0; m < 4; ++m)
        #pragma unroll
        for (int j = 0; j < 4; ++j) {
            int row = row0 + wr * 64 + m * 16 + rg * 4 + j;
            float v0 = acc[m][0][j] + b0;
            float v1 = acc[m][1][j] + b1;
            if (RELU) { v0 = fmaxf(v0, 0.f); v1 = fmaxf(v1, 0.f); }
            C[(size_t)row * DEMB_ + col0 + wc * 32 + cl]      = f2bf(v0);
            C[(size_t)row * DEMB_ + col0 + wc * 32 + 16 + cl] = f2bf(v1);
        }
}

// ---------------- projection GEMM (dual), A=fp32 gathered via srcrows ----------------
template<int K, bool RELU>
__global__ __launch_bounds__(512, 4) void egemm_f32a_g_dual(ProjDual P)
{
    const int side = blockIdx.y;
    const int bid = blockIdx.x;
    const int row0 = (bid >> 2) * 128, col0 = (bid & 3) * 128;
    if (row0 >= *P.Nr[side]) return;
    const float* A = P.A[side];
    const unsigned short* Wt = P.Wt[side];
    const float* bias = P.bias[side];
    unsigned short* C = P.C[side];
    const int* srcrows = P.srcrows[side];
    const int Mmax = P.Mmax[side];

    __shared__ __align__(16) unsigned char Abuf[128 * 64 * 2];
    __shared__ __align__(16) unsigned char Bbuf[128 * 64 * 2];
    const int t = threadIdx.x;
    const int wave = t >> 6, lane = t & 63;
    const int wr = wave >> 2, wc = wave & 3;
    const int cl = lane & 15, rg = lane >> 4;

    const int pr0 = t >> 3, pq0 = t & 7;
    const int pr1 = pr0 + 64;
    const int ks0 = ((pq0 ^ (pr0 & 7)) * 8);
    const int ks1 = ((pq0 ^ (pr1 & 7)) * 8);
    const int ad0 = pr0 * 128 + ((pq0 ^ (pr0 & 7)) << 4);
    const int ad1 = pr1 * 128 + ((pq0 ^ (pr1 & 7)) << 4);
    const int sr0 = clampi(srcrows[row0 + pr0], Mmax - 1);
    const int sr1 = clampi(srcrows[row0 + pr1], Mmax - 1);
    const float* Ar0 = A + (size_t)sr0 * K;
    const float* Ar1 = A + (size_t)sr1 * K;
    const unsigned short* Bglob = Wt + (size_t)col0 * K;

    int aoff[4], asw[4], boff[2], bsw[2];
    #pragma unroll
    for (int m = 0; m < 4; ++m) {
        int r = wr * 64 + m * 16 + cl;
        aoff[m] = r * 128; asw[m] = (r & 7) << 4;
    }
    #pragma unroll
    for (int n = 0; n < 2; ++n) {
        int c = wc * 32 + n * 16 + cl;
        boff[n] = c * 128; bsw[n] = (c & 7) << 4;
    }

    f32x4 acc[4][2];
    #pragma unroll
    for (int m = 0; m < 4; ++m) {
        acc[m][0] = (f32x4){0.f, 0.f, 0.f, 0.f};
        acc[m][1] = (f32x4){0.f, 0.f, 0.f, 0.f};
    }
    for (int k0 = 0; k0 < K; k0 += 64) {
        gld_lds16(Bglob + (size_t)pr0 * K + k0 + ks0, Bbuf + t * 16);
        gld_lds16(Bglob + (size_t)pr1 * K + k0 + ks1, Bbuf + (t + 512) * 16);
        {
            const float* s0 = Ar0 + k0 + pq0 * 8;
            const float* s1 = Ar1 + k0 + pq0 * 8;
            float4 u0 = *(const float4*)(s0), u1 = *(const float4*)(s0 + 4);
            float4 u2 = *(const float4*)(s1), u3 = *(const float4*)(s1 + 4);
            ushort8 w0, w1;
            w0[0] = f2bf(u0.x); w0[1] = f2bf(u0.y); w0[2] = f2bf(u0.z); w0[3] = f2bf(u0.w);
            w0[4] = f2bf(u1.x); w0[5] = f2bf(u1.y); w0[6] = f2bf(u1.z); w0[7] = f2bf(u1.w);
            w1[0] = f2bf(u2.x); w1[1] = f2bf(u2.y); w1[2] = f2bf(u2.z); w1[3] = f2bf(u2.w);
            w1[4] = f2bf(u3.x); w1[5] = f2bf(u3.y); w1[6] = f2bf(u3.z); w1[7] = f2bf(u3.w);
            *(ushort8*)(Abuf + ad0) = w0;
            *(ushort8*)(Abuf + ad1) = w1;
        }
        __syncthreads();
        #pragma unroll
        for (int h = 0; h < 2; ++h) {
            const int cb = h * 64 + rg * 16;
            short8 av[4], bv[2];
            #pragma unroll
            for (int m = 0; m < 4; ++m)
                av[m] = *(const short8*)(Abuf + aoff[m] + (cb ^ asw[m]));
            #pragma unroll
            for (int n = 0; n < 2; ++n)
                bv[n] = *(const short8*)(Bbuf + boff[n] + (cb ^ bsw[n]));
            #pragma unroll
            for (int m = 0; m < 4; ++m)
                #pragma unroll
                for (int n = 0; n < 2; ++n)
                    acc[m][n] = __builtin_amdgcn_mfma_f32_16x16x32_bf16(
                        av[m], bv[n], acc[m][n], 0, 0, 0);
        }
        __syncthreads();
    }
    const float b0 = bias[col0 + wc * 32 + cl];
    const float b1 = bias[col0 + wc * 32 + 16 + cl];
    #pragma unroll
    for (int m = 0; m < 4; ++m)
        #pragma unroll
        for (int j = 0; j < 4; ++j) {
            int row = row0 + wr * 64 + m * 16 + rg * 4 + j;
            float v0 = acc[m][0][j] + b0;
            float v1 = acc[m][1][j] + b1;
            if (RELU) { v0 = fmaxf(v0, 0.f); v1 = fmaxf(v1, 0.f); }
            C[(size_t)row * DEMB_ + col0 + wc * 32 + cl]      = f2bf(v0);
            C[(size_t)row * DEMB_ + col0 + wc * 32 + 16 + cl] = f2bf(v1);
        }
}

// ---------------- LayerNorm (dual, bf16 in/out), one wave per row ----------------
__global__ __launch_bounds__(256) void ln_bf16_dual(LnDual P)
{
    const int side = blockIdx.y;
    const int lane = threadIdx.x & 63;
    const int row = blockIdx.x * 4 + (threadIdx.x >> 6);
    if (row >= *P.Nr[side]) return;
    unsigned short* p = P.h[side] + (size_t)row * DEMB_;
    const float* g = P.g[side];
    const float* b = P.b[side];
    ushort8 v = *(const ushort8*)(p + lane * 8);
    float x[8];
    #pragma unroll
    for (int i = 0; i < 8; ++i) x[i] = bf2f(v[i]);
    float s = 0.f;
    #pragma unroll
    for (int i = 0; i < 8; ++i) s += x[i];
    #pragma unroll
    for (int d = 32; d >= 1; d >>= 1) s += __shfl_xor(s, d);
    float mu = s * (1.f / DEMB_);
    float sq = 0.f;
    #pragma unroll
    for (int i = 0; i < 8; ++i) { float dd = x[i] - mu; sq += dd * dd; }
    #pragma unroll
    for (int d = 32; d >= 1; d >>= 1) sq += __shfl_xor(sq, d);
    float rs = 1.f / sqrtf(sq * (1.f / DEMB_) + LN_EPS_);
    float4 g0 = *(const float4*)(g + lane * 8);
    float4 g1 = *(const float4*)(g + lane * 8 + 4);
    float4 b0 = *(const float4*)(b + lane * 8);
    float4 b1 = *(const float4*)(b + lane * 8 + 4);
    float gg[8] = {g0.x, g0.y, g0.z, g0.w, g1.x, g1.y, g1.z, g1.w};
    float bb[8] = {b0.x, b0.y, b0.z, b0.w, b1.x, b1.y, b1.z, b1.w};
    ushort8 o;
    #pragma unroll
    for (int i = 0; i < 8; ++i) o[i] = f2bf((x[i] - mu) * rs * gg[i] + bb[i]);
    *(ushort8*)(p + lane * 8) = o;
}

// ---------------- L2 normalize rows (dual, bf16 in -> bf16 out) ----------------
__global__ __launch_bounds__(256) void l2norm_bf16_dual(L2Dual P)
{
    const int side = blockIdx.y;
    const int lane = threadIdx.x & 63;
    const int row = blockIdx.x * 4 + (threadIdx.x >> 6);
    if (row >= *P.Nr[side]) return;
    const unsigned short* p = P.h[side] + (size_t)row * DEMB_;
    ushort8 v = *(const ushort8*)(p + lane * 8);
    float x[8];
    #pragma unroll
    for (int i = 0; i < 8; ++i) x[i] = bf2f(v[i]);
    float sq = 0.f;
    #pragma unroll
    for (int i = 0; i < 8; ++i) sq += x[i] * x[i];
    #pragma unroll
    for (int d = 32; d >= 1; d >>= 1) sq += __shfl_xor(sq, d);
    float rs = 1.f / sqrtf(sq);
    ushort8 w;
    #pragma unroll
    for (int i = 0; i < 8; ++i) w[i] = f2bf(x[i] * rs);
    *(ushort8*)(P.o[side] + (size_t)row * DEMB_ + lane * 8) = w;
}

// ---------------- sim partial: persistent CTAs, 64x128 tile, 2 waves ----------------
// Grid = 1536 blocks (6/CU); each grid-strides over 16384 work items.
// 1536 % 8 == 0 keeps item&7 (XCD slice) invariant per block.
#define SIM_ITEMS_ (NBAT_ * NBAT_ * 2 * 8)
#define SIM_BLOCKS_ 1536
__global__ __launch_bounds__(128, 3) void sim_part_kernel(
    const unsigned short* __restrict__ hA,  // bf16 compacted [<=4096,512]
    const unsigned short* __restrict__ hB,  // bf16 compacted [<=32768,512]
    const int* __restrict__ offA, const int* __restrict__ cntA,
    const int* __restrict__ offB, const int* __restrict__ cntB,
    const float* __restrict__ temp,
    float* __restrict__ rowmax_ws,   // [32][32][8][128]
    float* __restrict__ colmax_ws)   // [32][32][2][1024]
{
    __shared__ __align__(16) unsigned char Abuf[64 * 64 * 2];    // 8KB
    __shared__ __align__(16) unsigned char Bbuf[128 * 64 * 2];   // 16KB
    __shared__ float rowpart[2][64];

    const int t = threadIdx.x;
    const int w = t >> 6, lane = t & 63;
    const int cl = lane & 15, rg = lane >> 4;
    const float invT = 1.0f / temp[0];
    const int pr = t >> 3, pq = t & 7;     // pr in [0,16)
    const int ks = (pq ^ (pr & 7)) * 8;    // (pr+16i)&7 == pr&7

    int aoff[4], asw[4], boff[4], bsw[4];
    #pragma unroll
    for (int m = 0; m < 4; ++m) {
        int r = m * 16 + cl;
        aoff[m] = r * 128; asw[m] = (r & 7) << 4;
    }
    #pragma unroll
    for (int n = 0; n < 4; ++n) {
        int c = w * 64 + n * 16 + cl;
        boff[n] = c * 128; bsw[n] = (c & 7) << 4;
    }

    for (int item = blockIdx.x; item < SIM_ITEMS_; item += SIM_BLOCKS_) {
        const int g = (item & 7) * 2048 + (item >> 3);
        const int b = g >> 9;
        const int a = (g >> 4) & 31;
        const int at = (g >> 3) & 1, a0 = at << 6;
        const int s0t = g & 7, s0 = s0t << 7;

        const int nBb = cntB[b];
        if (s0 >= nBb) continue;
        const int nAa = cntA[a];
        if (a0 >= nAa) continue;

        const int abase = offA[a] + a0 + pr;
        const int bbase = offB[b] + s0 + pr;
        const unsigned short* Ap[4];
        const unsigned short* Bp[8];
        #pragma unroll
        for (int i = 0; i < 4; ++i)
            Ap[i] = hA + (size_t)clampi(abase + 16 * i, NBAT_ * TA_ - 1) * DEMB_ + ks;
        #pragma unroll
        for (int i = 0; i < 8; ++i)
            Bp[i] = hB + (size_t)clampi(bbase + 16 * i, NBAT_ * TB_ - 1) * DEMB_ + ks;

        unsigned mabits = 0;
        #pragma unroll
        for (int m = 0; m < 4; ++m)
            #pragma unroll
            for (int j = 0; j < 4; ++j)
                if (a0 + m * 16 + rg * 4 + j < nAa) mabits |= 1u << (m * 4 + j);
        int mb[4];
        #pragma unroll
        for (int n = 0; n < 4; ++n)
            mb[n] = (s0 + w * 64 + n * 16 + cl) < nBb;

        f32x4 acc[4][4];
        #pragma unroll
        for (int m = 0; m < 4; ++m)
            #pragma unroll
            for (int n = 0; n < 4; ++n)
                acc[m][n] = (f32x4){0.f, 0.f, 0.f, 0.f};

        for (int k0 = 0; k0 < DEMB_; k0 += 64) {
            #pragma unroll
            for (int i = 0; i < 4; ++i)
                gld_lds16(Ap[i] + k0, Abuf + (t + 128 * i) * 16);
            #pragma unroll
            for (int i = 0; i < 8; ++i)
                gld_lds16(Bp[i] + k0, Bbuf + (t + 128 * i) * 16);
            __syncthreads();
            #pragma unroll
            for (int h = 0; h < 2; ++h) {
                const int cb = h * 64 + rg * 16;
                short8 av[4], bv[4];
                #pragma unroll
                for (int m = 0; m < 4; ++m)
                    av[m] = *(const short8*)(Abuf + aoff[m] + (cb ^ asw[m]));
                #pragma unroll
                for (int n = 0; n < 4; ++n)
                    bv[n] = *(const short8*)(Bbuf + boff[n] + (cb ^ bsw[n]));
                #pragma unroll
                for (int m = 0; m < 4; ++m)
                    #pragma unroll
                    for (int n = 0; n < 4; ++n)
                        acc[m][n] = __builtin_amdgcn_mfma_f32_16x16x32_bf16(
                            av[m], bv[n], acc[m][n], 0, 0, 0);
            }
            __syncthreads();
        }
        // ---- epilogue ----
        float rmax[4][4];
        float cmax[4] = {-FLT_MAX, -FLT_MAX, -FLT_MAX, -FLT_MAX};
        #pragma unroll
        for (int m = 0; m < 4; ++m)
            #pragma unroll
            for (int j = 0; j < 4; ++j) {
                const bool ra = (mabits >> (m * 4 + j)) & 1;
                float rm = -FLT_MAX;
                #pragma unroll
                for (int n = 0; n < 4; ++n) {
                    float v = (ra && mb[n]) ? acc[m][n][j] * invT : -FLT_MAX;
                    rm = fmaxf(rm, v);
                    cmax[n] = fmaxf(cmax[n], v);
                }
                rmax[m][j] = rm;
            }
        #pragma unroll
        for (int d = 1; d < 16; d <<= 1)
            #pragma unroll
            for (int m = 0; m < 4; ++m)
                #pragma unroll
                for (int j = 0; j < 4; ++j)
                    rmax[m][j] = fmaxf(rmax[m][j], __shfl_xor(rmax[m][j], d));
        if (cl == 0) {
            #pragma unroll
            for (int m = 0; m < 4; ++m)
                #pragma unroll
                for (int j = 0; j < 4; ++j)
                    rowpart[w][m * 16 + rg * 4 + j] = rmax[m][j];
        }
        #pragma unroll
        for (int n = 0; n < 4; ++n) {
            cmax[n] = fmaxf(cmax[n], __shfl_xor(cmax[n], 16));
            cmax[n] = fmaxf(cmax[n], __shfl_xor(cmax[n], 32));
        }
        if (rg == 0) {
            float* cw = colmax_ws + ((size_t)((a * NBAT_ + b) * 2 + at)) * TB_ + s0;
            #pragma unroll
            for (int n = 0; n < 4; ++n)
                cw[w * 64 + n * 16 + cl] = cmax[n];
        }
        __syncthreads();
        if (t < 64) {
            float r = fmaxf(rowpart[0][t], rowpart[1][t]);
            rowmax_ws[(((size_t)(a * NBAT_ + b)) * 8 + s0t) * 128 + a0 + t] = r;
        }
        __syncthreads();
    }
}

// ---------------- sim reduce: means over compacted entries per (a,b) ----------------
__global__ __launch_bounds__(256) void sim_reduce_kernel(
    const float* __restrict__ rowmax_ws, const float* __restrict__ colmax_ws,
    const int* __restrict__ cntA, const int* __restrict__ cntB,
    float* __restrict__ out)
{
    __shared__ float red[4][2];
    const int bid = blockIdx.x;
    const int a = bid >> 5, b = bid & 31;
    const int t = threadIdx.x, lane = t & 63, wave = t >> 6;
    const int nAa = cntA[a], nBb = cntB[b];
    const int nt = (nBb + 127) >> 7;

    float numA = 0.f, sumB = 0.f;
    if (t < 128 && t < nAa) {
        const float* rp = rowmax_ws + ((size_t)(a * NBAT_ + b)) * 8 * 128 + t;
        float r = -FLT_MAX;
        for (int s = 0; s < nt; ++s) r = fmaxf(r, rp[s * 128]);
        numA = r;
    }
    const float* cp0 = colmax_ws + ((size_t)(a * NBAT_ + b)) * 2 * TB_;
    const float* cp1 = cp0 + TB_;
    const bool two = nAa > 64;
    #pragma unroll
    for (int i = 0; i < 4; ++i) {
        int s = t + i * 256;
        if (s < nBb) {
            float v = cp0[s];
            if (two) v = fmaxf(v, cp1[s]);
            sumB += v;
        }
    }
    #pragma unroll
    for (int d = 32; d >= 1; d >>= 1) {
        numA += __shfl_xor(numA, d);
        sumB += __shfl_xor(sumB, d);
    }
    if (lane == 0) { red[wave][0] = numA; red[wave][1] = sumB; }
    __syncthreads();
    if (t == 0) {
        float n  = red[0][0] + red[1][0] + red[2][0] + red[3][0];
        float nb = red[0][1] + red[1][1] + red[2][1] + red[3][1];
        out[a * NBAT_ + b] = n / fmaxf((float)nAa, 1e-6f);
        out[NBAT_ * NBAT_ + a * NBAT_ + b] = nb / fmaxf((float)nBb, 1e-6f);
    }
}

// ---------------- launch ----------------
extern "C" void kernel_launch(void* const* d_in, const int* in_sizes, int n_in,
                              void* d_out, int out_size, void* d_ws, size_t ws_size,
                              hipStream_t stream)
{
    const float* pep_esm  = (const float*)d_in[0];
    const float* rec_esm  = (const float*)d_in[1];
    const int*   pep_mask = (const int*)d_in[2];
    const int*   rec_mask = (const int*)d_in[3];
    const float* temp     = (const float*)d_in[4];
    const float* pep_pw  = (const float*)d_in[5];
    const float* pep_pb  = (const float*)d_in[6];
    const float* pep_f1w = (const float*)d_in[7];
    const float* pep_f1b = (const float*)d_in[8];
    const float* pep_lng = (const float*)d_in[9];
    const float* pep_lnb = (const float*)d_in[10];
    const float* pep_f2w = (const float*)d_in[11];
    const float* pep_f2b = (const float*)d_in[12];
    const float* rec_pw  = (const float*)d_in[13];
    const float* rec_pb  = (const float*)d_in[14];
    const float* rec_f1w = (const float*)d_in[15];
    const float* rec_f1b = (const float*)d_in[16];
    const float* rec_lng = (const float*)d_in[17];
    const float* rec_lnb = (const float*)d_in[18];
    const float* rec_f2w = (const float*)d_in[19];
    const float* rec_f2b = (const float*)d_in[20];
    float* out = (float*)d_out;

    const int Mr = NBAT_ * TB_;   // 32768
    const int Mp = NBAT_ * TA_;   // 4096

    // workspace layout (bytes)
    char* base = (char*)d_ws;
    unsigned short* R1    = (unsigned short*)(base);                           // 32MB rec
    unsigned short* R2    = (unsigned short*)(base + ((size_t)32 << 20));      // 32MB rec
    unsigned short* hB_c  = (unsigned short*)(base + ((size_t)64 << 20));      // 32MB compacted
    unsigned short* hA_c  = (unsigned short*)(base + ((size_t)96 << 20));      // 4MB compacted
    unsigned short* wts   = (unsigned short*)(base + ((size_t)101 << 20));     // ~4.6MB
    unsigned short* rec_pwt  = wts;                    // 512x1280
    unsigned short* pep_pwt  = rec_pwt + 512 * 1280;
    unsigned short* rec_f1wt = pep_pwt + 512 * 1280;   // 512x512
    unsigned short* rec_f2wt = rec_f1wt + 512 * 512;
    unsigned short* pep_f1wt = rec_f2wt + 512 * 512;
    unsigned short* pep_f2wt = pep_f1wt + 512 * 512;
    // pep chain buffers alias sim's rowmax/colmax region (dead until sim)
    unsigned short* P1 = (unsigned short*)(base + ((size_t)106 << 20));        // 4MB pep
    unsigned short* P2 = (unsigned short*)(base + ((size_t)110 << 20));        // 4MB pep
    float* rowmax_ws = (float*)(base + ((size_t)106 << 20));                   // 4MB (after pep dead)
    float* colmax_ws = (float*)(base + ((size_t)110 << 20));                   // 8MB
    int* idxA = (int*)(base + ((size_t)118 << 20));                            // 16KB
    int* idxB = idxA + Mp;                                                     // 128KB
    int* cntA = idxB + Mr;      // 32
    int* cntB = cntA + NBAT_;   // 32
    int* offA = cntB + NBAT_;   // 32
    int* offB = offA + NBAT_;   // 32
    int* tot  = offB + NBAT_;   // tot[0]=NrA(pep), tot[1]=NrB(rec)
    int* srcA = tot + 2;        // 4096 ints
    int* srcB = srcA + Mp;      // 32768 ints

    dim3 b256(256);
    // compaction metadata
    compact_idx_kernel<<<dim3(NBAT_), dim3(64), 0, stream>>>(pep_mask, TA_, idxA, cntA);
    compact_idx_kernel<<<dim3(NBAT_), dim3(64), 0, stream>>>(rec_mask, TB_, idxB, cntB);
    offsets_kernel<<<dim3(1), dim3(64), 0, stream>>>(cntA, cntB, offA, offB, tot);
    srcrows_kernel<<<dim3(Mp / 256), b256, 0, stream>>>(idxA, offA, 7, srcA);
    srcrows_kernel<<<dim3(Mr / 256), b256, 0, stream>>>(idxB, offB, 10, srcB);

    // weight transpose+convert (batched)
    {
        WPack p1; p1.src[0] = rec_pw; p1.dst[0] = rec_pwt;
                  p1.src[1] = pep_pw; p1.dst[1] = pep_pwt;
                  p1.src[2] = rec_pw; p1.dst[2] = rec_pwt;
                  p1.src[3] = rec_pw; p1.dst[3] = rec_pwt;
        wtrans_multi_kernel<<<dim3(DIN_ / 32, DEMB_ / 32, 2), b256, 0, stream>>>(p1, DIN_, DEMB_);
        WPack p2; p2.src[0] = rec_f1w; p2.dst[0] = rec_f1wt;
                  p2.src[1] = rec_f2w; p2.dst[1] = rec_f2wt;
                  p2.src[2] = pep_f1w; p2.dst[2] = pep_f1wt;
                  p2.src[3] = pep_f2w; p2.dst[3] = pep_f2wt;
        wtrans_multi_kernel<<<dim3(DEMB_ / 32, DEMB_ / 32, 4), b256, 0, stream>>>(p2, DEMB_, DEMB_);
    }

    const int* NrRec = tot + 1;
    const int* NrPep = tot;
    const dim3 ggrid((Mr / 128) * 4, 2);    // 1024 x 2
    const dim3 ngrid(Mr / 4, 2);            // 8192 x 2

    // --- both encoders, dual-batched (side 0 = rec, side 1 = pep) ---
    {
        ProjDual P;
        P.A[0] = rec_esm;  P.A[1] = pep_esm;
        P.Wt[0] = rec_pwt; P.Wt[1] = pep_pwt;
        P.bias[0] = rec_pb; P.bias[1] = pep_pb;
        P.C[0] = R1; P.C[1] = P1;
        P.srcrows[0] = srcB; P.srcrows[1] = srcA;
        P.Nr[0] = NrRec; P.Nr[1] = NrPep;
        P.Mmax[0] = Mr; P.Mmax[1] = Mp;
        egemm_f32a_g_dual<DIN_, false><<<ggrid, dim3(512), 0, stream>>>(P);
    }
    {
        EncDual P;
        P.A[0] = R1; P.A[1] = P1;
        P.Wt[0] = rec_f1wt; P.Wt[1] = pep_f1wt;
        P.bias[0] = rec_f1b; P.bias[1] = pep_f1b;
        P.C[0] = R2; P.C[1] = P2;
        P.Nr[0] = NrRec; P.Nr[1] = NrPep;
        egemm_bf16_dual<DEMB_, true><<<ggrid, dim3(512), 0, stream>>>(P);
    }
    {
        LnDual P;
        P.h[0] = R2; P.h[1] = P2;
        P.g[0] = rec_lng; P.g[1] = pep_lng;
        P.b[0] = rec_lnb; P.b[1] = pep_lnb;
        P.Nr[0] = NrRec; P.Nr[1] = NrPep;
        ln_bf16_dual<<<ngrid, b256, 0, stream>>>(P);
    }
    {
        EncDual P;
        P.A[0] = R2; P.A[1] = P2;
        P.Wt[0] = rec_f2wt; P.Wt[1] = pep_f2wt;
        P.bias[0] = rec_f2b; P.bias[1] = pep_f2b;
        P.C[0] = R1; P.C[1] = P1;
        P.Nr[0] = NrRec; P.Nr[1] = NrPep;
        egemm_bf16_dual<DEMB_, false><<<ggrid, dim3(512), 0, stream>>>(P);
    }
    {
        L2Dual P;
        P.h[0] = R1; P.h[1] = P1;
        P.o[0] = hB_c; P.o[1] = hA_c;
        P.Nr[0] = NrRec; P.Nr[1] = NrPep;
        l2norm_bf16_dual<<<ngrid, b256, 0, stream>>>(P);
    }

    // --- similarity: persistent 64x128 tiles, then reduce ---
    sim_part_kernel<<<dim3(SIM_BLOCKS_), dim3(128), 0, stream>>>(
        hA_c, hB_c, offA, cntA, offB, cntB, temp, rowmax_ws, colmax_ws);
    sim_reduce_kernel<<<dim3(NBAT_ * NBAT_), b256, 0, stream>>>(
        rowmax_ws, colmax_ws, cntA, cntB, out);
}

// Round 16
// 264.137 us; speedup vs baseline: 1.2466x; 1.2466x over previous
//
#include <hip/hip_runtime.h>
#include <float.h>
#include <stddef.h>
#include <stdint.h>

#define DIN_   1280
#define DEMB_  512
#define NBAT_  32
#define TA_    128
#define TB_    1024
#define LN_EPS_ 1e-5f

using short8  = __attribute__((ext_vector_type(8))) short;
using ushort8 = __attribute__((ext_vector_type(8))) unsigned short;
using f32x4   = __attribute__((ext_vector_type(4))) float;

typedef const __attribute__((address_space(1))) unsigned int gu32;
typedef __attribute__((address_space(3))) unsigned int lu32;

__device__ __forceinline__ void gld_lds16(const void* g, void* l) {
    __builtin_amdgcn_global_load_lds((gu32*)g, (lu32*)l, 16, 0, 0);
}

__device__ __forceinline__ unsigned short f2bf(float x) {
    unsigned u = __float_as_uint(x);
    u += 0x7FFFu + ((u >> 16) & 1u);
    return (unsigned short)(u >> 16);
}
__device__ __forceinline__ float bf2f(unsigned short u) {
    return __uint_as_float((unsigned)u << 16);
}
__device__ __forceinline__ int clampi(int v, int hi) {
    return v < 0 ? 0 : (v > hi ? hi : v);
}

// ---------------- compaction indices ----------------
__global__ __launch_bounds__(64) void compact_idx_kernel(
    const int* __restrict__ mask, int T, int* __restrict__ idx, int* __restrict__ cnt)
{
    const int b = blockIdx.x, lane = threadIdx.x;
    const int base = b * T;
    int run = 0;
    for (int c = 0; c < T; c += 64) {
        int m = mask[base + c + lane] != 0;
        unsigned long long bal = __ballot(m);
        int pos = run + __popcll(bal & ((1ull << lane) - 1ull));
        idx[base + c + lane] = m ? pos : -1;
        run += __popcll(bal);
    }
    if (lane == 0) cnt[b] = run;
}

__global__ __launch_bounds__(64) void offsets_kernel(
    const int* __restrict__ cntA, const int* __restrict__ cntB,
    int* __restrict__ offA, int* __restrict__ offB, int* __restrict__ tot)
{
    if (threadIdx.x == 0) {
        int s = 0;
        for (int i = 0; i < NBAT_; ++i) { offA[i] = s; s += cntA[i]; }
        tot[0] = s;
        s = 0;
        for (int i = 0; i < NBAT_; ++i) { offB[i] = s; s += cntB[i]; }
        tot[1] = s;
    }
}

__global__ __launch_bounds__(256) void srcrows_kernel(
    const int* __restrict__ idx, const int* __restrict__ off, int shift,
    int* __restrict__ srcrows)
{
    int r = blockIdx.x * 256 + threadIdx.x;
    int d = idx[r];
    if (d >= 0) srcrows[off[r >> shift] + d] = r;
}

// ---------------- weight transpose+convert (batched) ----------------
struct WPack { const float* src[4]; unsigned short* dst[4]; };
__global__ __launch_bounds__(256) void wtrans_multi_kernel(WPack p, int K, int N)
{
    __shared__ float tile[32][33];
    const float* W = p.src[blockIdx.z];
    unsigned short* Wt = p.dst[blockIdx.z];
    const int k0 = blockIdx.x * 32, n0 = blockIdx.y * 32;
    const int r = threadIdx.x >> 5, c = threadIdx.x & 31;
    #pragma unroll
    for (int i = 0; i < 4; ++i)
        tile[r + i * 8][c] = W[(size_t)(k0 + r + i * 8) * N + n0 + c];
    __syncthreads();
    #pragma unroll
    for (int i = 0; i < 4; ++i)
        Wt[(size_t)(n0 + r + i * 8) * K + k0 + c] = f2bf(tile[c][r + i * 8]);
}

// ---------------- dual-side parameter packs ----------------
struct EncDual {
    const unsigned short* A[2];
    const unsigned short* Wt[2];
    const float* bias[2];
    unsigned short* C[2];
    const int* Nr[2];
};
struct ProjDual {
    const float* A[2];
    const unsigned short* Wt[2];
    const float* bias[2];
    unsigned short* C[2];
    const int* srcrows[2];
    const int* Nr[2];
    int Mmax[2];
};
struct LnDual { unsigned short* h[2]; const float* g[2]; const float* b[2]; const int* Nr[2]; };
struct L2Dual { const unsigned short* h[2]; unsigned short* o[2]; const int* Nr[2]; };

// ---------------- encoder GEMM (dual), A=bf16 compacted [*,K] ----------------
template<int K, bool RELU>
__global__ __launch_bounds__(512, 4) void egemm_bf16_dual(EncDual P)
{
    const int side = blockIdx.y;
    const int bid = blockIdx.x;
    const int row0 = (bid >> 2) * 128, col0 = (bid & 3) * 128;
    if (row0 >= *P.Nr[side]) return;
    const unsigned short* A = P.A[side];
    const unsigned short* Wt = P.Wt[side];
    const float* bias = P.bias[side];
    unsigned short* C = P.C[side];

    __shared__ __align__(16) unsigned char Abuf[128 * 64 * 2];
    __shared__ __align__(16) unsigned char Bbuf[128 * 64 * 2];
    const int t = threadIdx.x;
    const int wave = t >> 6, lane = t & 63;
    const int wr = wave >> 2, wc = wave & 3;
    const int cl = lane & 15, rg = lane >> 4;

    const int pr0 = t >> 3, pq0 = t & 7;
    const int pr1 = pr0 + 64;
    const int ks0 = ((pq0 ^ (pr0 & 7)) * 8);
    const int ks1 = ((pq0 ^ (pr1 & 7)) * 8);
    const unsigned short* Aglob = A + (size_t)row0 * K;
    const unsigned short* Bglob = Wt + (size_t)col0 * K;

    int aoff[4], asw[4], boff[2], bsw[2];
    #pragma unroll
    for (int m = 0; m < 4; ++m) {
        int r = wr * 64 + m * 16 + cl;
        aoff[m] = r * 128; asw[m] = (r & 7) << 4;
    }
    #pragma unroll
    for (int n = 0; n < 2; ++n) {
        int c = wc * 32 + n * 16 + cl;
        boff[n] = c * 128; bsw[n] = (c & 7) << 4;
    }

    f32x4 acc[4][2];
    #pragma unroll
    for (int m = 0; m < 4; ++m) {
        acc[m][0] = (f32x4){0.f, 0.f, 0.f, 0.f};
        acc[m][1] = (f32x4){0.f, 0.f, 0.f, 0.f};
    }
    for (int k0 = 0; k0 < K; k0 += 64) {
        gld_lds16(Aglob + (size_t)pr0 * K + k0 + ks0, Abuf + t * 16);
        gld_lds16(Aglob + (size_t)pr1 * K + k0 + ks1, Abuf + (t + 512) * 16);
        gld_lds16(Bglob + (size_t)pr0 * K + k0 + ks0, Bbuf + t * 16);
        gld_lds16(Bglob + (size_t)pr1 * K + k0 + ks1, Bbuf + (t + 512) * 16);
        __syncthreads();
        #pragma unroll
        for (int h = 0; h < 2; ++h) {
            const int cb = h * 64 + rg * 16;
            short8 av[4], bv[2];
            #pragma unroll
            for (int m = 0; m < 4; ++m)
                av[m] = *(const short8*)(Abuf + aoff[m] + (cb ^ asw[m]));
            #pragma unroll
            for (int n = 0; n < 2; ++n)
                bv[n] = *(const short8*)(Bbuf + boff[n] + (cb ^ bsw[n]));
            #pragma unroll
            for (int m = 0; m < 4; ++m)
                #pragma unroll
                for (int n = 0; n < 2; ++n)
                    acc[m][n] = __builtin_amdgcn_mfma_f32_16x16x32_bf16(
                        av[m], bv[n], acc[m][n], 0, 0, 0);
        }
        __syncthreads();
    }
    const float b0 = bias[col0 + wc * 32 + cl];
    const float b1 = bias[col0 + wc * 32 + 16 + cl];
    #pragma unroll
    for (int m = 0; m < 4; ++m)
        #pragma unroll
        for (int j = 0; j < 4; ++j) {
            int row = row0 + wr * 64 + m * 16 + rg * 4 + j;
            float v0 = acc[m][0][j] + b0;
            float v1 = acc[m][1][j] + b1;
            if (RELU) { v0 = fmaxf(v0, 0.f); v1 = fmaxf(v1, 0.f); }
            C[(size_t)row * DEMB_ + col0 + wc * 32 + cl]      = f2bf(v0);
            C[(size_t)row * DEMB_ + col0 + wc * 32 + 16 + cl] = f2bf(v1);
        }
}

// ---------------- projection GEMM (dual), A=fp32 gathered via srcrows ----------------
template<int K, bool RELU>
__global__ __launch_bounds__(512, 4) void egemm_f32a_g_dual(ProjDual P)
{
    const int side = blockIdx.y;
    const int bid = blockIdx.x;
    const int row0 = (bid >> 2) * 128, col0 = (bid & 3) * 128;
    if (row0 >= *P.Nr[side]) return;
    const float* A = P.A[side];
    const unsigned short* Wt = P.Wt[side];
    const float* bias = P.bias[side];
    unsigned short* C = P.C[side];
    const int* srcrows = P.srcrows[side];
    const int Mmax = P.Mmax[side];

    __shared__ __align__(16) unsigned char Abuf[128 * 64 * 2];
    __shared__ __align__(16) unsigned char Bbuf[128 * 64 * 2];
    const int t = threadIdx.x;
    const int wave = t >> 6, lane = t & 63;
    const int wr = wave >> 2, wc = wave & 3;
    const int cl = lane & 15, rg = lane >> 4;

    const int pr0 = t >> 3, pq0 = t & 7;
    const int pr1 = pr0 + 64;
    const int ks0 = ((pq0 ^ (pr0 & 7)) * 8);
    const int ks1 = ((pq0 ^ (pr1 & 7)) * 8);
    const int ad0 = pr0 * 128 + ((pq0 ^ (pr0 & 7)) << 4);
    const int ad1 = pr1 * 128 + ((pq0 ^ (pr1 & 7)) << 4);
    const int sr0 = clampi(srcrows[row0 + pr0], Mmax - 1);
    const int sr1 = clampi(srcrows[row0 + pr1], Mmax - 1);
    const float* Ar0 = A + (size_t)sr0 * K;
    const float* Ar1 = A + (size_t)sr1 * K;
    const unsigned short* Bglob = Wt + (size_t)col0 * K;

    int aoff[4], asw[4], boff[2], bsw[2];
    #pragma unroll
    for (int m = 0; m < 4; ++m) {
        int r = wr * 64 + m * 16 + cl;
        aoff[m] = r * 128; asw[m] = (r & 7) << 4;
    }
    #pragma unroll
    for (int n = 0; n < 2; ++n) {
        int c = wc * 32 + n * 16 + cl;
        boff[n] = c * 128; bsw[n] = (c & 7) << 4;
    }

    f32x4 acc[4][2];
    #pragma unroll
    for (int m = 0; m < 4; ++m) {
        acc[m][0] = (f32x4){0.f, 0.f, 0.f, 0.f};
        acc[m][1] = (f32x4){0.f, 0.f, 0.f, 0.f};
    }
    for (int k0 = 0; k0 < K; k0 += 64) {
        gld_lds16(Bglob + (size_t)pr0 * K + k0 + ks0, Bbuf + t * 16);
        gld_lds16(Bglob + (size_t)pr1 * K + k0 + ks1, Bbuf + (t + 512) * 16);
        {
            const float* s0 = Ar0 + k0 + pq0 * 8;
            const float* s1 = Ar1 + k0 + pq0 * 8;
            float4 u0 = *(const float4*)(s0), u1 = *(const float4*)(s0 + 4);
            float4 u2 = *(const float4*)(s1), u3 = *(const float4*)(s1 + 4);
            ushort8 w0, w1;
            w0[0] = f2bf(u0.x); w0[1] = f2bf(u0.y); w0[2] = f2bf(u0.z); w0[3] = f2bf(u0.w);
            w0[4] = f2bf(u1.x); w0[5] = f2bf(u1.y); w0[6] = f2bf(u1.z); w0[7] = f2bf(u1.w);
            w1[0] = f2bf(u2.x); w1[1] = f2bf(u2.y); w1[2] = f2bf(u2.z); w1[3] = f2bf(u2.w);
            w1[4] = f2bf(u3.x); w1[5] = f2bf(u3.y); w1[6] = f2bf(u3.z); w1[7] = f2bf(u3.w);
            *(ushort8*)(Abuf + ad0) = w0;
            *(ushort8*)(Abuf + ad1) = w1;
        }
        __syncthreads();
        #pragma unroll
        for (int h = 0; h < 2; ++h) {
            const int cb = h * 64 + rg * 16;
            short8 av[4], bv[2];
            #pragma unroll
            for (int m = 0; m < 4; ++m)
                av[m] = *(const short8*)(Abuf + aoff[m] + (cb ^ asw[m]));
            #pragma unroll
            for (int n = 0; n < 2; ++n)
                bv[n] = *(const short8*)(Bbuf + boff[n] + (cb ^ bsw[n]));
            #pragma unroll
            for (int m = 0; m < 4; ++m)
                #pragma unroll
                for (int n = 0; n < 2; ++n)
                    acc[m][n] = __builtin_amdgcn_mfma_f32_16x16x32_bf16(
                        av[m], bv[n], acc[m][n], 0, 0, 0);
        }
        __syncthreads();
    }
    const float b0 = bias[col0 + wc * 32 + cl];
    const float b1 = bias[col0 + wc * 32 + 16 + cl];
    #pragma unroll
    for (int m = 0; m < 4; ++m)
        #pragma unroll
        for (int j = 0; j < 4; ++j) {
            int row = row0 + wr * 64 + m * 16 + rg * 4 + j;
            float v0 = acc[m][0][j] + b0;
            float v1 = acc[m][1][j] + b1;
            if (RELU) { v0 = fmaxf(v0, 0.f); v1 = fmaxf(v1, 0.f); }
            C[(size_t)row * DEMB_ + col0 + wc * 32 + cl]      = f2bf(v0);
            C[(size_t)row * DEMB_ + col0 + wc * 32 + 16 + cl] = f2bf(v1);
        }
}

// ---------------- LayerNorm (dual, bf16 in/out), one wave per row ----------------
__global__ __launch_bounds__(256) void ln_bf16_dual(LnDual P)
{
    const int side = blockIdx.y;
    const int lane = threadIdx.x & 63;
    const int row = blockIdx.x * 4 + (threadIdx.x >> 6);
    if (row >= *P.Nr[side]) return;
    unsigned short* p = P.h[side] + (size_t)row * DEMB_;
    const float* g = P.g[side];
    const float* b = P.b[side];
    ushort8 v = *(const ushort8*)(p + lane * 8);
    float x[8];
    #pragma unroll
    for (int i = 0; i < 8; ++i) x[i] = bf2f(v[i]);
    float s = 0.f;
    #pragma unroll
    for (int i = 0; i < 8; ++i) s += x[i];
    #pragma unroll
    for (int d = 32; d >= 1; d >>= 1) s += __shfl_xor(s, d);
    float mu = s * (1.f / DEMB_);
    float sq = 0.f;
    #pragma unroll
    for (int i = 0; i < 8; ++i) { float dd = x[i] - mu; sq += dd * dd; }
    #pragma unroll
    for (int d = 32; d >= 1; d >>= 1) sq += __shfl_xor(sq, d);
    float rs = 1.f / sqrtf(sq * (1.f / DEMB_) + LN_EPS_);
    float4 g0 = *(const float4*)(g + lane * 8);
    float4 g1 = *(const float4*)(g + lane * 8 + 4);
    float4 b0 = *(const float4*)(b + lane * 8);
    float4 b1 = *(const float4*)(b + lane * 8 + 4);
    float gg[8] = {g0.x, g0.y, g0.z, g0.w, g1.x, g1.y, g1.z, g1.w};
    float bb[8] = {b0.x, b0.y, b0.z, b0.w, b1.x, b1.y, b1.z, b1.w};
    ushort8 o;
    #pragma unroll
    for (int i = 0; i < 8; ++i) o[i] = f2bf((x[i] - mu) * rs * gg[i] + bb[i]);
    *(ushort8*)(p + lane * 8) = o;
}

// ---------------- L2 normalize rows (dual, bf16 in -> bf16 out) ----------------
__global__ __launch_bounds__(256) void l2norm_bf16_dual(L2Dual P)
{
    const int side = blockIdx.y;
    const int lane = threadIdx.x & 63;
    const int row = blockIdx.x * 4 + (threadIdx.x >> 6);
    if (row >= *P.Nr[side]) return;
    const unsigned short* p = P.h[side] + (size_t)row * DEMB_;
    ushort8 v = *(const ushort8*)(p + lane * 8);
    float x[8];
    #pragma unroll
    for (int i = 0; i < 8; ++i) x[i] = bf2f(v[i]);
    float sq = 0.f;
    #pragma unroll
    for (int i = 0; i < 8; ++i) sq += x[i] * x[i];
    #pragma unroll
    for (int d = 32; d >= 1; d >>= 1) sq += __shfl_xor(sq, d);
    float rs = 1.f / sqrtf(sq);
    ushort8 w;
    #pragma unroll
    for (int i = 0; i < 8; ++i) w[i] = f2bf(x[i] * rs);
    *(ushort8*)(P.o[side] + (size_t)row * DEMB_ + lane * 8) = w;
}

// ---------------- sim partial: 64x128 tile, 2 waves, 64x64 per wave (acc 4x4) ----------------
// Proven R12 version: dispatch grid 16384 blocks, early exit on empty tiles.
__global__ __launch_bounds__(128, 3) void sim_part_kernel(
    const unsigned short* __restrict__ hA,  // bf16 compacted [<=4096,512]
    const unsigned short* __restrict__ hB,  // bf16 compacted [<=32768,512]
    const int* __restrict__ offA, const int* __restrict__ cntA,
    const int* __restrict__ offB, const int* __restrict__ cntB,
    const float* __restrict__ temp,
    float* __restrict__ rowmax_ws,   // [32][32][8][128]
    float* __restrict__ colmax_ws)   // [32][32][2][1024]
{
    __shared__ __align__(16) unsigned char Abuf[64 * 64 * 2];    // 8KB
    __shared__ __align__(16) unsigned char Bbuf[128 * 64 * 2];   // 16KB
    __shared__ float rowpart[2][64];

    const int bid = blockIdx.x;
    const int g = (bid & 7) * 2048 + (bid >> 3);   // XCD gets 4 consecutive b
    const int b = g >> 9;
    const int a = (g >> 4) & 31;
    const int at = (g >> 3) & 1, a0 = at << 6;
    const int s0t = g & 7, s0 = s0t << 7;

    const int nBb = cntB[b];
    if (s0 >= nBb) return;
    const int nAa = cntA[a];
    if (a0 >= nAa) return;

    const int t = threadIdx.x;
    const int w = t >> 6, lane = t & 63;
    const int cl = lane & 15, rg = lane >> 4;
    const float invT = 1.0f / temp[0];

    const int pr = t >> 3, pq = t & 7;     // pr in [0,16)
    const int ks = (pq ^ (pr & 7)) * 8;    // (pr+16i)&7 == pr&7
    const int abase = offA[a] + a0 + pr;
    const int bbase = offB[b] + s0 + pr;
    const unsigned short* Ap[4];
    const unsigned short* Bp[8];
    #pragma unroll
    for (int i = 0; i < 4; ++i)
        Ap[i] = hA + (size_t)clampi(abase + 16 * i, NBAT_ * TA_ - 1) * DEMB_ + ks;
    #pragma unroll
    for (int i = 0; i < 8; ++i)
        Bp[i] = hB + (size_t)clampi(bbase + 16 * i, NBAT_ * TB_ - 1) * DEMB_ + ks;

    unsigned mabits = 0;
    #pragma unroll
    for (int m = 0; m < 4; ++m)
        #pragma unroll
        for (int j = 0; j < 4; ++j)
            if (a0 + m * 16 + rg * 4 + j < nAa) mabits |= 1u << (m * 4 + j);
    int mb[4];
    #pragma unroll
    for (int n = 0; n < 4; ++n)
        mb[n] = (s0 + w * 64 + n * 16 + cl) < nBb;

    int aoff[4], asw[4], boff[4], bsw[4];
    #pragma unroll
    for (int m = 0; m < 4; ++m) {
        int r = m * 16 + cl;
        aoff[m] = r * 128; asw[m] = (r & 7) << 4;
    }
    #pragma unroll
    for (int n = 0; n < 4; ++n) {
        int c = w * 64 + n * 16 + cl;
        boff[n] = c * 128; bsw[n] = (c & 7) << 4;
    }

    f32x4 acc[4][4];
    #pragma unroll
    for (int m = 0; m < 4; ++m)
        #pragma unroll
        for (int n = 0; n < 4; ++n)
            acc[m][n] = (f32x4){0.f, 0.f, 0.f, 0.f};

    for (int k0 = 0; k0 < DEMB_; k0 += 64) {
        #pragma unroll
        for (int i = 0; i < 4; ++i)
            gld_lds16(Ap[i] + k0, Abuf + (t + 128 * i) * 16);
        #pragma unroll
        for (int i = 0; i < 8; ++i)
            gld_lds16(Bp[i] + k0, Bbuf + (t + 128 * i) * 16);
        __syncthreads();
        #pragma unroll
        for (int h = 0; h < 2; ++h) {
            const int cb = h * 64 + rg * 16;
            short8 av[4], bv[4];
            #pragma unroll
            for (int m = 0; m < 4; ++m)
                av[m] = *(const short8*)(Abuf + aoff[m] + (cb ^ asw[m]));
            #pragma unroll
            for (int n = 0; n < 4; ++n)
                bv[n] = *(const short8*)(Bbuf + boff[n] + (cb ^ bsw[n]));
            #pragma unroll
            for (int m = 0; m < 4; ++m)
                #pragma unroll
                for (int n = 0; n < 4; ++n)
                    acc[m][n] = __builtin_amdgcn_mfma_f32_16x16x32_bf16(
                        av[m], bv[n], acc[m][n], 0, 0, 0);
        }
        __syncthreads();
    }
    // ---- epilogue ----
    float rmax[4][4];
    float cmax[4] = {-FLT_MAX, -FLT_MAX, -FLT_MAX, -FLT_MAX};
    #pragma unroll
    for (int m = 0; m < 4; ++m)
        #pragma unroll
        for (int j = 0; j < 4; ++j) {
            const bool ra = (mabits >> (m * 4 + j)) & 1;
            float rm = -FLT_MAX;
            #pragma unroll
            for (int n = 0; n < 4; ++n) {
                float v = (ra && mb[n]) ? acc[m][n][j] * invT : -FLT_MAX;
                rm = fmaxf(rm, v);
                cmax[n] = fmaxf(cmax[n], v);
            }
            rmax[m][j] = rm;
        }
    #pragma unroll
    for (int d = 1; d < 16; d <<= 1)
        #pragma unroll
        for (int m = 0; m < 4; ++m)
            #pragma unroll
            for (int j = 0; j < 4; ++j)
                rmax[m][j] = fmaxf(rmax[m][j], __shfl_xor(rmax[m][j], d));
    if (cl == 0) {
        #pragma unroll
        for (int m = 0; m < 4; ++m)
            #pragma unroll
            for (int j = 0; j < 4; ++j)
                rowpart[w][m * 16 + rg * 4 + j] = rmax[m][j];
    }
    #pragma unroll
    for (int n = 0; n < 4; ++n) {
        cmax[n] = fmaxf(cmax[n], __shfl_xor(cmax[n], 16));
        cmax[n] = fmaxf(cmax[n], __shfl_xor(cmax[n], 32));
    }
    if (rg == 0) {
        float* cw = colmax_ws + ((size_t)((a * NBAT_ + b) * 2 + at)) * TB_ + s0;
        #pragma unroll
        for (int n = 0; n < 4; ++n)
            cw[w * 64 + n * 16 + cl] = cmax[n];
    }
    __syncthreads();
    if (t < 64) {
        float r = fmaxf(rowpart[0][t], rowpart[1][t]);
        rowmax_ws[(((size_t)(a * NBAT_ + b)) * 8 + s0t) * 128 + a0 + t] = r;
    }
}

// ---------------- sim reduce: means over compacted entries per (a,b) ----------------
__global__ __launch_bounds__(256) void sim_reduce_kernel(
    const float* __restrict__ rowmax_ws, const float* __restrict__ colmax_ws,
    const int* __restrict__ cntA, const int* __restrict__ cntB,
    float* __restrict__ out)
{
    __shared__ float red[4][2];
    const int bid = blockIdx.x;
    const int a = bid >> 5, b = bid & 31;
    const int t = threadIdx.x, lane = t & 63, wave = t >> 6;
    const int nAa = cntA[a], nBb = cntB[b];
    const int nt = (nBb + 127) >> 7;

    float numA = 0.f, sumB = 0.f;
    if (t < 128 && t < nAa) {
        const float* rp = rowmax_ws + ((size_t)(a * NBAT_ + b)) * 8 * 128 + t;
        float r = -FLT_MAX;
        for (int s = 0; s < nt; ++s) r = fmaxf(r, rp[s * 128]);
        numA = r;
    }
    const float* cp0 = colmax_ws + ((size_t)(a * NBAT_ + b)) * 2 * TB_;
    const float* cp1 = cp0 + TB_;
    const bool two = nAa > 64;
    #pragma unroll
    for (int i = 0; i < 4; ++i) {
        int s = t + i * 256;
        if (s < nBb) {
            float v = cp0[s];
            if (two) v = fmaxf(v, cp1[s]);
            sumB += v;
        }
    }
    #pragma unroll
    for (int d = 32; d >= 1; d >>= 1) {
        numA += __shfl_xor(numA, d);
        sumB += __shfl_xor(sumB, d);
    }
    if (lane == 0) { red[wave][0] = numA; red[wave][1] = sumB; }
    __syncthreads();
    if (t == 0) {
        float n  = red[0][0] + red[1][0] + red[2][0] + red[3][0];
        float nb = red[0][1] + red[1][1] + red[2][1] + red[3][1];
        out[a * NBAT_ + b] = n / fmaxf((float)nAa, 1e-6f);
        out[NBAT_ * NBAT_ + a * NBAT_ + b] = nb / fmaxf((float)nBb, 1e-6f);
    }
}

// ---------------- launch ----------------
extern "C" void kernel_launch(void* const* d_in, const int* in_sizes, int n_in,
                              void* d_out, int out_size, void* d_ws, size_t ws_size,
                              hipStream_t stream)
{
    const float* pep_esm  = (const float*)d_in[0];
    const float* rec_esm  = (const float*)d_in[1];
    const int*   pep_mask = (const int*)d_in[2];
    const int*   rec_mask = (const int*)d_in[3];
    const float* temp     = (const float*)d_in[4];
    const float* pep_pw  = (const float*)d_in[5];
    const float* pep_pb  = (const float*)d_in[6];
    const float* pep_f1w = (const float*)d_in[7];
    const float* pep_f1b = (const float*)d_in[8];
    const float* pep_lng = (const float*)d_in[9];
    const float* pep_lnb = (const float*)d_in[10];
    const float* pep_f2w = (const float*)d_in[11];
    const float* pep_f2b = (const float*)d_in[12];
    const float* rec_pw  = (const float*)d_in[13];
    const float* rec_pb  = (const float*)d_in[14];
    const float* rec_f1w = (const float*)d_in[15];
    const float* rec_f1b = (const float*)d_in[16];
    const float* rec_lng = (const float*)d_in[17];
    const float* rec_lnb = (const float*)d_in[18];
    const float* rec_f2w = (const float*)d_in[19];
    const float* rec_f2b = (const float*)d_in[20];
    float* out = (float*)d_out;

    const int Mr = NBAT_ * TB_;   // 32768
    const int Mp = NBAT_ * TA_;   // 4096

    // workspace layout (bytes)
    char* base = (char*)d_ws;
    unsigned short* R1    = (unsigned short*)(base);                           // 32MB rec
    unsigned short* R2    = (unsigned short*)(base + ((size_t)32 << 20));      // 32MB rec
    unsigned short* hB_c  = (unsigned short*)(base + ((size_t)64 << 20));      // 32MB compacted
    unsigned short* hA_c  = (unsigned short*)(base + ((size_t)96 << 20));      // 4MB compacted
    unsigned short* wts   = (unsigned short*)(base + ((size_t)101 << 20));     // ~4.6MB
    unsigned short* rec_pwt  = wts;                    // 512x1280
    unsigned short* pep_pwt  = rec_pwt + 512 * 1280;
    unsigned short* rec_f1wt = pep_pwt + 512 * 1280;   // 512x512
    unsigned short* rec_f2wt = rec_f1wt + 512 * 512;
    unsigned short* pep_f1wt = rec_f2wt + 512 * 512;
    unsigned short* pep_f2wt = pep_f1wt + 512 * 512;
    // pep chain buffers alias sim's rowmax/colmax region (dead until sim)
    unsigned short* P1 = (unsigned short*)(base + ((size_t)106 << 20));        // 4MB pep
    unsigned short* P2 = (unsigned short*)(base + ((size_t)110 << 20));        // 4MB pep
    float* rowmax_ws = (float*)(base + ((size_t)106 << 20));                   // 4MB (after pep dead)
    float* colmax_ws = (float*)(base + ((size_t)110 << 20));                   // 8MB
    int* idxA = (int*)(base + ((size_t)118 << 20));                            // 16KB
    int* idxB = idxA + Mp;                                                     // 128KB
    int* cntA = idxB + Mr;      // 32
    int* cntB = cntA + NBAT_;   // 32
    int* offA = cntB + NBAT_;   // 32
    int* offB = offA + NBAT_;   // 32
    int* tot  = offB + NBAT_;   // tot[0]=NrA(pep), tot[1]=NrB(rec)
    int* srcA = tot + 2;        // 4096 ints
    int* srcB = srcA + Mp;      // 32768 ints

    dim3 b256(256);
    // compaction metadata
    compact_idx_kernel<<<dim3(NBAT_), dim3(64), 0, stream>>>(pep_mask, TA_, idxA, cntA);
    compact_idx_kernel<<<dim3(NBAT_), dim3(64), 0, stream>>>(rec_mask, TB_, idxB, cntB);
    offsets_kernel<<<dim3(1), dim3(64), 0, stream>>>(cntA, cntB, offA, offB, tot);
    srcrows_kernel<<<dim3(Mp / 256), b256, 0, stream>>>(idxA, offA, 7, srcA);
    srcrows_kernel<<<dim3(Mr / 256), b256, 0, stream>>>(idxB, offB, 10, srcB);

    // weight transpose+convert (batched)
    {
        WPack p1; p1.src[0] = rec_pw; p1.dst[0] = rec_pwt;
                  p1.src[1] = pep_pw; p1.dst[1] = pep_pwt;
                  p1.src[2] = rec_pw; p1.dst[2] = rec_pwt;
                  p1.src[3] = rec_pw; p1.dst[3] = rec_pwt;
        wtrans_multi_kernel<<<dim3(DIN_ / 32, DEMB_ / 32, 2), b256, 0, stream>>>(p1, DIN_, DEMB_);
        WPack p2; p2.src[0] = rec_f1w; p2.dst[0] = rec_f1wt;
                  p2.src[1] = rec_f2w; p2.dst[1] = rec_f2wt;
                  p2.src[2] = pep_f1w; p2.dst[2] = pep_f1wt;
                  p2.src[3] = pep_f2w; p2.dst[3] = pep_f2wt;
        wtrans_multi_kernel<<<dim3(DEMB_ / 32, DEMB_ / 32, 4), b256, 0, stream>>>(p2, DEMB_, DEMB_);
    }

    const int* NrRec = tot + 1;
    const int* NrPep = tot;
    const dim3 ggrid((Mr / 128) * 4, 2);    // 1024 x 2
    const dim3 ngrid(Mr / 4, 2);            // 8192 x 2

    // --- both encoders, dual-batched (side 0 = rec, side 1 = pep) ---
    {
        ProjDual P;
        P.A[0] = rec_esm;  P.A[1] = pep_esm;
        P.Wt[0] = rec_pwt; P.Wt[1] = pep_pwt;
        P.bias[0] = rec_pb; P.bias[1] = pep_pb;
        P.C[0] = R1; P.C[1] = P1;
        P.srcrows[0] = srcB; P.srcrows[1] = srcA;
        P.Nr[0] = NrRec; P.Nr[1] = NrPep;
        P.Mmax[0] = Mr; P.Mmax[1] = Mp;
        egemm_f32a_g_dual<DIN_, false><<<ggrid, dim3(512), 0, stream>>>(P);
    }
    {
        EncDual P;
        P.A[0] = R1; P.A[1] = P1;
        P.Wt[0] = rec_f1wt; P.Wt[1] = pep_f1wt;
        P.bias[0] = rec_f1b; P.bias[1] = pep_f1b;
        P.C[0] = R2; P.C[1] = P2;
        P.Nr[0] = NrRec; P.Nr[1] = NrPep;
        egemm_bf16_dual<DEMB_, true><<<ggrid, dim3(512), 0, stream>>>(P);
    }
    {
        LnDual P;
        P.h[0] = R2; P.h[1] = P2;
        P.g[0] = rec_lng; P.g[1] = pep_lng;
        P.b[0] = rec_lnb; P.b[1] = pep_lnb;
        P.Nr[0] = NrRec; P.Nr[1] = NrPep;
        ln_bf16_dual<<<ngrid, b256, 0, stream>>>(P);
    }
    {
        EncDual P;
        P.A[0] = R2; P.A[1] = P2;
        P.Wt[0] = rec_f2wt; P.Wt[1] = pep_f2wt;
        P.bias[0] = rec_f2b; P.bias[1] = pep_f2b;
        P.C[0] = R1; P.C[1] = P1;
        P.Nr[0] = NrRec; P.Nr[1] = NrPep;
        egemm_bf16_dual<DEMB_, false><<<ggrid, dim3(512), 0, stream>>>(P);
    }
    {
        L2Dual P;
        P.h[0] = R1; P.h[1] = P1;
        P.o[0] = hB_c; P.o[1] = hA_c;
        P.Nr[0] = NrRec; P.Nr[1] = NrPep;
        l2norm_bf16_dual<<<ngrid, b256, 0, stream>>>(P);
    }

    // --- similarity: 64x128 tiles over compacted rows, then reduce ---
    sim_part_kernel<<<dim3(NBAT_ * NBAT_ * 2 * 8), dim3(128), 0, stream>>>(
        hA_c, hB_c, offA, cntA, offB, cntB, temp, rowmax_ws, colmax_ws);
    sim_reduce_kernel<<<dim3(NBAT_ * NBAT_), b256, 0, stream>>>(
        rowmax_ws, colmax_ws, cntA, cntB, out);
}